// Round 1
// baseline (5225.207 us; speedup 1.0000x reference)
//
#include <hip/hip_runtime.h>
#include <math.h>

#define B_   2
#define L_   1024
#define DM   768
#define NL   2
#define DI   1536
#define DTR  48
#define NTOK (B_ * L_)   // 2048

// ---------------------------------------------------------------------------
// block-wide reduction of two floats (256 threads, wave64)
// ---------------------------------------------------------------------------
__device__ __forceinline__ void blockReduce2(float& a, float& b) {
    #pragma unroll
    for (int off = 32; off; off >>= 1) {
        a += __shfl_down(a, off);
        b += __shfl_down(b, off);
    }
    __shared__ float sa[4], sb[4];
    int lane = threadIdx.x & 63, w = threadIdx.x >> 6;
    if (lane == 0) { sa[w] = a; sb[w] = b; }
    __syncthreads();
    if (threadIdx.x == 0) {
        float ta = 0.f, tb = 0.f;
        #pragma unroll
        for (int i = 0; i < 4; i++) { ta += sa[i]; tb += sb[i]; }
        sa[0] = ta; sb[0] = tb;
    }
    __syncthreads();
    a = sa[0]; b = sb[0];
}

// ---------------------------------------------------------------------------
// copy x into both branch buffers
// ---------------------------------------------------------------------------
__global__ void copy2_kernel(const float* __restrict__ x,
                             float* __restrict__ xs, float* __restrict__ xl) {
    int i = blockIdx.x * 256 + threadIdx.x;
    float v = x[i];
    xs[i] = v;
    xl[i] = v;
}

// ---------------------------------------------------------------------------
// RMSNorm: out = x * rsqrt(mean(x^2)+1e-5) * w      (one block per row)
// ---------------------------------------------------------------------------
__global__ void rmsnorm_kernel(const float* __restrict__ x,
                               const float* __restrict__ w,
                               float* __restrict__ out) {
    int n = blockIdx.x;
    const float* xr = x + (size_t)n * DM;
    float v[3];
    float ss = 0.f, dummy = 0.f;
    #pragma unroll
    for (int j = 0; j < 3; j++) {
        v[j] = xr[threadIdx.x + 256 * j];
        ss += v[j] * v[j];
    }
    blockReduce2(ss, dummy);
    float scale = rsqrtf(ss / DM + 1e-5f);
    #pragma unroll
    for (int j = 0; j < 3; j++) {
        int m = threadIdx.x + 256 * j;
        out[(size_t)n * DM + m] = v[j] * scale * w[m];
    }
}

// ---------------------------------------------------------------------------
// Tiled fp32 GEMM, NT layout: C[n,m] = sum_k A[n,k] * W[m,k]
// A: (NTOK,K) stride lda; W: (M,K) row-major; C: (NTOK,M) stride ldc
// ACT: 0 none, 1 softplus.  BIAS: add bias[m].  RES: C += existing C.
// ---------------------------------------------------------------------------
template<int ACT, bool BIAS, bool RES>
__global__ __launch_bounds__(256) void gemm_nt(
        const float* __restrict__ A, int lda,
        const float* __restrict__ W,
        const float* __restrict__ bias,
        float* __restrict__ C, int ldc,
        int M, int K) {
    __shared__ float As[16][65];
    __shared__ float Bs[16][65];
    int n0 = blockIdx.x * 64;
    int m0 = blockIdx.y * 64;
    int tid = threadIdx.x;
    int tx = tid & 15, ty = tid >> 4;
    int arow = tid >> 2;           // 0..63
    int kq = (tid & 3) * 4;        // 0,4,8,12
    float acc[4][4] = {};

    for (int kt = 0; kt < K; kt += 16) {
        {   // A tile (64 rows x 16 k), stored transposed
            const float4 v = *(const float4*)(A + (size_t)(n0 + arow) * lda + kt + kq);
            As[kq + 0][arow] = v.x; As[kq + 1][arow] = v.y;
            As[kq + 2][arow] = v.z; As[kq + 3][arow] = v.w;
        }
        {   // W tile
            int m = m0 + arow;
            float4 v = make_float4(0.f, 0.f, 0.f, 0.f);
            if (m < M) v = *(const float4*)(W + (size_t)m * K + kt + kq);
            Bs[kq + 0][arow] = v.x; Bs[kq + 1][arow] = v.y;
            Bs[kq + 2][arow] = v.z; Bs[kq + 3][arow] = v.w;
        }
        __syncthreads();
        #pragma unroll
        for (int k = 0; k < 16; k++) {
            float av[4], bv[4];
            #pragma unroll
            for (int i = 0; i < 4; i++) av[i] = As[k][ty * 4 + i];
            #pragma unroll
            for (int j = 0; j < 4; j++) bv[j] = Bs[k][tx * 4 + j];
            #pragma unroll
            for (int i = 0; i < 4; i++)
                #pragma unroll
                for (int j = 0; j < 4; j++)
                    acc[i][j] += av[i] * bv[j];
        }
        __syncthreads();
    }

    #pragma unroll
    for (int i = 0; i < 4; i++) {
        int row = n0 + ty * 4 + i;
        #pragma unroll
        for (int j = 0; j < 4; j++) {
            int col = m0 + tx * 4 + j;
            if (col < M) {
                float v = acc[i][j];
                if (BIAS) v += bias[col];
                if (ACT == 1) v = (v > 20.f) ? v : log1pf(__expf(v));
                float* cp = C + (size_t)row * ldc + col;
                if (RES) v += *cp;
                *cp = v;
            }
        }
    }
}

// ---------------------------------------------------------------------------
// Depthwise causal conv along L (+bias, +SiLU).  Input = first DI cols of xz.
// ---------------------------------------------------------------------------
template<int K>
__global__ void conv_silu_kernel(const float* __restrict__ xz,
                                 const float* __restrict__ cw,
                                 const float* __restrict__ cb,
                                 float* __restrict__ xi) {
    int idx = blockIdx.x * 256 + threadIdx.x;   // over NTOK*DI
    int c = idx % DI;
    int n = idx / DI;       // n = b*L + l
    int l = n % L_;
    float acc = cb[c];
    #pragma unroll
    for (int k = 0; k < K; k++) {
        int lp = l - (K - 1) + k;
        if (lp >= 0)
            acc += xz[(size_t)(n - (K - 1) + k) * (2 * DI) + c] * cw[c * K + k];
    }
    xi[(size_t)n * DI + c] = acc / (1.f + __expf(-acc));
}

// ---------------------------------------------------------------------------
// Selective scan.  One thread per (b,d,s); S-lane shuffle reduce for y.
// Writes u = (y + x*D) * silu(z) in-place into xi.
// ---------------------------------------------------------------------------
template<int S>
__global__ void scan_kernel(const float* __restrict__ delta,
                            const float* __restrict__ dbc,
                            float* __restrict__ xi,
                            const float* __restrict__ xz,
                            const float* __restrict__ A_log,
                            const float* __restrict__ Dp) {
    int tid = blockIdx.x * 64 + threadIdx.x;
    int s = tid % S;
    int gd = tid / S;          // b*DI + d
    int d = gd % DI;
    int b = gd / DI;
    float a  = -__expf(A_log[d * S + s]);
    float Dv = Dp[d];
    float h = 0.f;
    const float* drow = delta + (size_t)b * L_ * DI + d;
    float*       xrow = xi    + (size_t)b * L_ * DI + d;
    const float* bc   = dbc   + (size_t)b * L_ * 128 + DTR;
    const float* zp   = xz    + (size_t)b * L_ * 2 * DI + DI + d;

    for (int t = 0; t < L_; ++t) {
        float dlt = drow[(size_t)t * DI];
        float x   = xrow[(size_t)t * DI];
        float bv  = bc[t * 128 + s];
        float cv  = bc[t * 128 + S + s];
        h = __expf(dlt * a) * h + (dlt * x) * bv;
        float p = h * cv;
        #pragma unroll
        for (int off = S >> 1; off; off >>= 1) p += __shfl_xor(p, off);
        if (s == 0) {
            float z = zp[(size_t)t * 2 * DI];
            float y = p + x * Dv;
            xrow[(size_t)t * DI] = y * (z / (1.f + __expf(-z)));
        }
    }
}

// ---------------------------------------------------------------------------
// pack xc = concat(xs, xl) along features
// ---------------------------------------------------------------------------
__global__ void pack_xc_kernel(const float* __restrict__ xs,
                               const float* __restrict__ xl,
                               float* __restrict__ xc) {
    int idx = blockIdx.x * 256 + threadIdx.x;   // NTOK*2*DM
    int n = idx / (2 * DM);
    int m = idx % (2 * DM);
    xc[idx] = (m < DM) ? xs[(size_t)n * DM + m] : xl[(size_t)n * DM + m - DM];
}

// ---------------------------------------------------------------------------
// final: gated mix + LayerNorm  (one block per row)
// gp row layout: [0:768] gate preact, [768:1536] proj
// ---------------------------------------------------------------------------
__global__ void fuse_ln_kernel(const float* __restrict__ xs,
                               const float* __restrict__ xl,
                               const float* __restrict__ gp,
                               const float* __restrict__ ln_w,
                               const float* __restrict__ ln_b,
                               float* __restrict__ out) {
    int n = blockIdx.x;
    float v[3];
    float sum = 0.f, sumsq = 0.f;
    #pragma unroll
    for (int j = 0; j < 3; j++) {
        int m = threadIdx.x + 256 * j;
        float g    = gp[(size_t)n * (2 * DM) + m];
        float gate = 1.f / (1.f + __expf(-g));
        float p    = gp[(size_t)n * (2 * DM) + DM + m];
        float val  = gate * xs[(size_t)n * DM + m]
                   + (1.f - gate) * xl[(size_t)n * DM + m] + p;
        v[j] = val;
        sum += val; sumsq += val * val;
    }
    blockReduce2(sum, sumsq);
    float mean = sum / DM;
    float var  = sumsq / DM - mean * mean;
    float inv  = rsqrtf(var + 1e-5f);
    #pragma unroll
    for (int j = 0; j < 3; j++) {
        int m = threadIdx.x + 256 * j;
        out[(size_t)n * DM + m] = (v[j] - mean) * inv * ln_w[m] + ln_b[m];
    }
}

// ---------------------------------------------------------------------------
extern "C" void kernel_launch(void* const* d_in, const int* in_sizes, int n_in,
                              void* d_out, int out_size, void* d_ws, size_t ws_size,
                              hipStream_t stream) {
    const float* x      = (const float*)d_in[0];
    const float* gate_w = (const float*)d_in[21];
    const float* gate_b = (const float*)d_in[22];
    const float* proj_w = (const float*)d_in[23];
    const float* proj_b = (const float*)d_in[24];
    const float* ln_w   = (const float*)d_in[25];
    const float* ln_b   = (const float*)d_in[26];

    float* ws = (float*)d_ws;
    size_t off = 0;
    float* xs    = ws + off; off += (size_t)NTOK * DM;          // 1.57M
    float* xl    = ws + off; off += (size_t)NTOK * DM;
    float* xn    = ws + off; off += (size_t)NTOK * DM;
    float* xz    = ws + off; off += (size_t)NTOK * 2 * DI;      // 6.29M
    float* xi    = ws + off; off += (size_t)NTOK * DI;
    float* dbc   = ws + off; off += (size_t)NTOK * 128;
    float* delta = ws + off; off += (size_t)NTOK * DI;
    // total ~17.56M floats = 70.3 MB

    copy2_kernel<<<(NTOK * DM) / 256, 256, 0, stream>>>(x, xs, xl);

    for (int br = 0; br < 2; ++br) {
        const float* in_w   = (const float*)d_in[1 + 10 * br + 0];
        const float* conv_w = (const float*)d_in[1 + 10 * br + 1];
        const float* conv_b = (const float*)d_in[1 + 10 * br + 2];
        const float* x_w    = (const float*)d_in[1 + 10 * br + 3];
        const float* dt_w   = (const float*)d_in[1 + 10 * br + 4];
        const float* dt_b   = (const float*)d_in[1 + 10 * br + 5];
        const float* A_log  = (const float*)d_in[1 + 10 * br + 6];
        const float* Dp     = (const float*)d_in[1 + 10 * br + 7];
        const float* out_w  = (const float*)d_in[1 + 10 * br + 8];
        const float* norm_w = (const float*)d_in[1 + 10 * br + 9];
        const int S = br ? 32 : 16;
        const int Kc = br ? 9 : 3;
        const int Mdbc = DTR + 2 * S;    // 80 / 112
        float* xbuf = br ? xl : xs;

        for (int i = 0; i < NL; ++i) {
            rmsnorm_kernel<<<NTOK, 256, 0, stream>>>(xbuf, norm_w + i * DM, xn);

            dim3 g1(NTOK / 64, (2 * DI) / 64);
            gemm_nt<0, false, false><<<g1, 256, 0, stream>>>(
                xn, DM, in_w + (size_t)i * 2 * DI * DM, nullptr,
                xz, 2 * DI, 2 * DI, DM);

            if (br == 0)
                conv_silu_kernel<3><<<(NTOK * DI) / 256, 256, 0, stream>>>(
                    xz, conv_w + i * DI * 3, conv_b + i * DI, xi);
            else
                conv_silu_kernel<9><<<(NTOK * DI) / 256, 256, 0, stream>>>(
                    xz, conv_w + i * DI * 9, conv_b + i * DI, xi);

            dim3 g2(NTOK / 64, (Mdbc + 63) / 64);
            gemm_nt<0, false, false><<<g2, 256, 0, stream>>>(
                xi, DI, x_w + (size_t)i * Mdbc * DI, nullptr,
                dbc, 128, Mdbc, DI);

            dim3 g3(NTOK / 64, DI / 64);
            gemm_nt<1, true, false><<<g3, 256, 0, stream>>>(
                dbc, 128, dt_w + (size_t)i * DI * DTR, dt_b + i * DI,
                delta, DI, DI, DTR);

            if (br == 0)
                scan_kernel<16><<<(B_ * DI * 16) / 64, 64, 0, stream>>>(
                    delta, dbc, xi, xz, A_log + (size_t)i * DI * 16, Dp + i * DI);
            else
                scan_kernel<32><<<(B_ * DI * 32) / 64, 64, 0, stream>>>(
                    delta, dbc, xi, xz, A_log + (size_t)i * DI * 32, Dp + i * DI);

            dim3 g4(NTOK / 64, DM / 64);
            gemm_nt<0, false, true><<<g4, 256, 0, stream>>>(
                xi, DI, out_w + (size_t)i * DM * DI, nullptr,
                xbuf, DM, DM, DI);
        }
    }

    // ---- fusion head ----
    float* xc = xz;                              // NTOK*1536
    float* gp = xz + (size_t)NTOK * 2 * DM;      // NTOK*1536 (fits in xz region)
    pack_xc_kernel<<<(NTOK * 2 * DM) / 256, 256, 0, stream>>>(xs, xl, xc);

    dim3 g5(NTOK / 64, DM / 64);
    gemm_nt<0, true, false><<<g5, 256, 0, stream>>>(
        xc, 2 * DM, gate_w, gate_b, gp, 2 * DM, DM, 2 * DM);
    gemm_nt<0, true, false><<<g5, 256, 0, stream>>>(
        xc, 2 * DM, proj_w, proj_b, gp + DM, 2 * DM, DM, 2 * DM);

    fuse_ln_kernel<<<NTOK, 256, 0, stream>>>(
        xs, xl, gp, ln_w, ln_b, (float*)d_out);
}

// Round 2
// 3504.825 us; speedup vs baseline: 1.4909x; 1.4909x over previous
//
#include <hip/hip_runtime.h>
#include <math.h>

#define B_   2
#define L_   1024
#define DM   768
#define NL   2
#define DI   1536
#define DTR  48
#define NTOK (B_ * L_)   // 2048

// ---------------------------------------------------------------------------
// block-wide reduction of two floats (256 threads, wave64)
// ---------------------------------------------------------------------------
__device__ __forceinline__ void blockReduce2(float& a, float& b) {
    #pragma unroll
    for (int off = 32; off; off >>= 1) {
        a += __shfl_down(a, off);
        b += __shfl_down(b, off);
    }
    __shared__ float sa[4], sb[4];
    int lane = threadIdx.x & 63, w = threadIdx.x >> 6;
    if (lane == 0) { sa[w] = a; sb[w] = b; }
    __syncthreads();
    if (threadIdx.x == 0) {
        float ta = 0.f, tb = 0.f;
        #pragma unroll
        for (int i = 0; i < 4; i++) { ta += sa[i]; tb += sb[i]; }
        sa[0] = ta; sb[0] = tb;
    }
    __syncthreads();
    a = sa[0]; b = sb[0];
}

// ---------------------------------------------------------------------------
__global__ void copy2_kernel(const float* __restrict__ x,
                             float* __restrict__ xs, float* __restrict__ xl) {
    int i = blockIdx.x * 256 + threadIdx.x;
    float v = x[i];
    xs[i] = v;
    xl[i] = v;
}

// ---------------------------------------------------------------------------
__global__ void rmsnorm_kernel(const float* __restrict__ x,
                               const float* __restrict__ w,
                               float* __restrict__ out) {
    int n = blockIdx.x;
    const float* xr = x + (size_t)n * DM;
    float v[3];
    float ss = 0.f, dummy = 0.f;
    #pragma unroll
    for (int j = 0; j < 3; j++) {
        v[j] = xr[threadIdx.x + 256 * j];
        ss += v[j] * v[j];
    }
    blockReduce2(ss, dummy);
    float scale = rsqrtf(ss / DM + 1e-5f);
    #pragma unroll
    for (int j = 0; j < 3; j++) {
        int m = threadIdx.x + 256 * j;
        out[(size_t)n * DM + m] = v[j] * scale * w[m];
    }
}

// ---------------------------------------------------------------------------
// Tiled fp32 GEMM, NT layout: C[n,m] = sum_k A[n,k] * W[m,k]
// ---------------------------------------------------------------------------
template<int ACT, bool BIAS, bool RES>
__global__ __launch_bounds__(256) void gemm_nt(
        const float* __restrict__ A, int lda,
        const float* __restrict__ W,
        const float* __restrict__ bias,
        float* __restrict__ C, int ldc,
        int M, int K) {
    __shared__ float As[16][65];
    __shared__ float Bs[16][65];
    int n0 = blockIdx.x * 64;
    int m0 = blockIdx.y * 64;
    int tid = threadIdx.x;
    int tx = tid & 15, ty = tid >> 4;
    int arow = tid >> 2;           // 0..63
    int kq = (tid & 3) * 4;        // 0,4,8,12
    float acc[4][4] = {};

    for (int kt = 0; kt < K; kt += 16) {
        {
            const float4 v = *(const float4*)(A + (size_t)(n0 + arow) * lda + kt + kq);
            As[kq + 0][arow] = v.x; As[kq + 1][arow] = v.y;
            As[kq + 2][arow] = v.z; As[kq + 3][arow] = v.w;
        }
        {
            int m = m0 + arow;
            float4 v = make_float4(0.f, 0.f, 0.f, 0.f);
            if (m < M) v = *(const float4*)(W + (size_t)m * K + kt + kq);
            Bs[kq + 0][arow] = v.x; Bs[kq + 1][arow] = v.y;
            Bs[kq + 2][arow] = v.z; Bs[kq + 3][arow] = v.w;
        }
        __syncthreads();
        #pragma unroll
        for (int k = 0; k < 16; k++) {
            float av[4], bv[4];
            #pragma unroll
            for (int i = 0; i < 4; i++) av[i] = As[k][ty * 4 + i];
            #pragma unroll
            for (int j = 0; j < 4; j++) bv[j] = Bs[k][tx * 4 + j];
            #pragma unroll
            for (int i = 0; i < 4; i++)
                #pragma unroll
                for (int j = 0; j < 4; j++)
                    acc[i][j] += av[i] * bv[j];
        }
        __syncthreads();
    }

    #pragma unroll
    for (int i = 0; i < 4; i++) {
        int row = n0 + ty * 4 + i;
        #pragma unroll
        for (int j = 0; j < 4; j++) {
            int col = m0 + tx * 4 + j;
            if (col < M) {
                float v = acc[i][j];
                if (BIAS) v += bias[col];
                if (ACT == 1) v = (v > 20.f) ? v : log1pf(__expf(v));
                float* cp = C + (size_t)row * ldc + col;
                if (RES) v += *cp;
                *cp = v;
            }
        }
    }
}

// ---------------------------------------------------------------------------
// Depthwise causal conv along L (+bias, +SiLU).
// ---------------------------------------------------------------------------
template<int K>
__global__ void conv_silu_kernel(const float* __restrict__ xz,
                                 const float* __restrict__ cw,
                                 const float* __restrict__ cb,
                                 float* __restrict__ xi) {
    int idx = blockIdx.x * 256 + threadIdx.x;   // over NTOK*DI
    int c = idx % DI;
    int n = idx / DI;       // n = b*L + l
    int l = n % L_;
    float acc = cb[c];
    #pragma unroll
    for (int k = 0; k < K; k++) {
        int lp = l - (K - 1) + k;
        if (lp >= 0)
            acc += xz[(size_t)(n - (K - 1) + k) * (2 * DI) + c] * cw[c * K + k];
    }
    xi[(size_t)n * DI + c] = acc / (1.f + __expf(-acc));
}

// ---------------------------------------------------------------------------
// Chunked selective scan.
// Thread layout (all phases): gid = ((b*DI + d)*NC + c)*S + s  (phase 1/3)
//                             gid = (b*DI + d)*S + s           (phase 2)
// Phase 1: per-chunk local scan from h=0. Emits:
//   yloc[t]  (xz xi-columns, stride 2*DI)   = C_t . h_local_t
//   cumd[t]  (in place over delta)          = sum_{u<=t in chunk} delta_u
//   dec[gid] = exp(a * chunk_delta_sum), hfin[gid] = local final h
// ---------------------------------------------------------------------------
template<int S, int NC>
__global__ void scan_phase1(float* __restrict__ delta,       // read + cumd write
                            const float* __restrict__ dbc,
                            const float* __restrict__ xi,
                            float* __restrict__ yloc,        // xz base
                            const float* __restrict__ A_log,
                            float* __restrict__ dec,
                            float* __restrict__ hfin) {
    const int CL = L_ / NC;
    int gid = blockIdx.x * 256 + threadIdx.x;
    int s  = gid % S;
    int c  = (gid / S) % NC;
    int gd = gid / (S * NC);
    int d  = gd % DI;
    int b  = gd / DI;

    float a = -__expf(A_log[d * S + s]);
    float h = 0.f, dsum = 0.f;

    size_t rowbase = (size_t)b * L_ + (size_t)c * CL;
    float*       drow = delta + rowbase * DI + d;
    const float* xrow = xi    + rowbase * DI + d;
    const float* bc   = dbc   + rowbase * 128 + DTR;
    float*       yrow = yloc  + rowbase * (2 * DI) + d;

    for (int t = 0; t < CL; ++t) {
        float dlt = drow[(size_t)t * DI];
        float x   = xrow[(size_t)t * DI];
        float bv  = bc[t * 128 + s];
        float cv  = bc[t * 128 + S + s];
        dsum += dlt;
        h = __expf(dlt * a) * h + (dlt * x) * bv;
        float p = h * cv;
        #pragma unroll
        for (int off = S >> 1; off; off >>= 1) p += __shfl_xor(p, off);
        if (s == 0) {
            yrow[(size_t)t * (2 * DI)] = p;
            drow[(size_t)t * DI]       = dsum;   // cumd overwrites delta
        }
    }
    dec[gid]  = __expf(a * dsum);
    hfin[gid] = h;
}

// Phase 2: sequential over chunks; hfin[idx] becomes h_start for that chunk.
template<int S, int NC>
__global__ void scan_phase2(const float* __restrict__ dec,
                            float* __restrict__ hfin) {
    int gid = blockIdx.x * 256 + threadIdx.x;  // (b*DI+d)*S + s
    int s  = gid % S;
    int gd = gid / S;
    float run = 0.f;
    #pragma unroll
    for (int c = 0; c < NC; ++c) {
        size_t idx = ((size_t)gd * NC + c) * S + s;
        float dc = dec[idx];
        float hf = hfin[idx];
        hfin[idx] = run;
        run = dc * run + hf;
    }
}

// Phase 3 (no serial dependence): y = yloc + C.(exp(a*cumd)*h_start) + x*D,
// then y *= silu(z); written into xi.
template<int S, int NC>
__global__ void scan_phase3(const float* __restrict__ cumd,
                            const float* __restrict__ dbc,
                            float* __restrict__ xi,
                            const float* __restrict__ xz,   // yloc + z
                            const float* __restrict__ A_log,
                            const float* __restrict__ Dp,
                            const float* __restrict__ hstart) {
    const int CL = L_ / NC;
    int gid = blockIdx.x * 256 + threadIdx.x;
    int s  = gid % S;
    int c  = (gid / S) % NC;
    int gd = gid / (S * NC);
    int d  = gd % DI;
    int b  = gd / DI;

    float a  = -__expf(A_log[d * S + s]);
    float hs = hstart[gid];
    float Dv = Dp[d];

    size_t rowbase = (size_t)b * L_ + (size_t)c * CL;
    const float* cdrow = cumd + rowbase * DI + d;
    const float* bcC   = dbc  + rowbase * 128 + DTR + S;
    float*       xrow  = xi   + rowbase * DI + d;
    const float* yrow  = xz   + rowbase * (2 * DI) + d;
    const float* zrow  = xz   + rowbase * (2 * DI) + DI + d;

    for (int t = 0; t < CL; ++t) {
        float cd = cdrow[(size_t)t * DI];
        float cv = bcC[t * 128 + s];
        float p  = __expf(a * cd) * hs * cv;
        #pragma unroll
        for (int off = S >> 1; off; off >>= 1) p += __shfl_xor(p, off);
        if (s == 0) {
            float x  = xrow[(size_t)t * DI];
            float yl = yrow[(size_t)t * (2 * DI)];
            float z  = zrow[(size_t)t * (2 * DI)];
            float y  = yl + p + x * Dv;
            xrow[(size_t)t * DI] = y * (z / (1.f + __expf(-z)));
        }
    }
}

// ---------------------------------------------------------------------------
__global__ void pack_xc_kernel(const float* __restrict__ xs,
                               const float* __restrict__ xl,
                               float* __restrict__ xc) {
    int idx = blockIdx.x * 256 + threadIdx.x;   // NTOK*2*DM
    int n = idx / (2 * DM);
    int m = idx % (2 * DM);
    xc[idx] = (m < DM) ? xs[(size_t)n * DM + m] : xl[(size_t)n * DM + m - DM];
}

// ---------------------------------------------------------------------------
__global__ void fuse_ln_kernel(const float* __restrict__ xs,
                               const float* __restrict__ xl,
                               const float* __restrict__ gp,
                               const float* __restrict__ ln_w,
                               const float* __restrict__ ln_b,
                               float* __restrict__ out) {
    int n = blockIdx.x;
    float v[3];
    float sum = 0.f, sumsq = 0.f;
    #pragma unroll
    for (int j = 0; j < 3; j++) {
        int m = threadIdx.x + 256 * j;
        float g    = gp[(size_t)n * (2 * DM) + m];
        float gate = 1.f / (1.f + __expf(-g));
        float p    = gp[(size_t)n * (2 * DM) + DM + m];
        float val  = gate * xs[(size_t)n * DM + m]
                   + (1.f - gate) * xl[(size_t)n * DM + m] + p;
        v[j] = val;
        sum += val; sumsq += val * val;
    }
    blockReduce2(sum, sumsq);
    float mean = sum / DM;
    float var  = sumsq / DM - mean * mean;
    float inv  = rsqrtf(var + 1e-5f);
    #pragma unroll
    for (int j = 0; j < 3; j++) {
        int m = threadIdx.x + 256 * j;
        out[(size_t)n * DM + m] = (v[j] - mean) * inv * ln_w[m] + ln_b[m];
    }
}

// ---------------------------------------------------------------------------
extern "C" void kernel_launch(void* const* d_in, const int* in_sizes, int n_in,
                              void* d_out, int out_size, void* d_ws, size_t ws_size,
                              hipStream_t stream) {
    const float* x      = (const float*)d_in[0];
    const float* gate_w = (const float*)d_in[21];
    const float* gate_b = (const float*)d_in[22];
    const float* proj_w = (const float*)d_in[23];
    const float* proj_b = (const float*)d_in[24];
    const float* ln_w   = (const float*)d_in[25];
    const float* ln_b   = (const float*)d_in[26];

    float* ws = (float*)d_ws;
    size_t off = 0;
    float* xs    = ws + off; off += (size_t)NTOK * DM;
    float* xl    = ws + off; off += (size_t)NTOK * DM;
    float* xn    = ws + off; off += (size_t)NTOK * DM;      // also chunk-state
    float* xz    = ws + off; off += (size_t)NTOK * 2 * DI;
    float* xi    = ws + off; off += (size_t)NTOK * DI;
    float* dbc   = ws + off; off += (size_t)NTOK * 128;
    float* delta = ws + off; off += (size_t)NTOK * DI;
    // total ~17.56M floats = 70.3 MB (unchanged)

    copy2_kernel<<<(NTOK * DM) / 256, 256, 0, stream>>>(x, xs, xl);

    for (int br = 0; br < 2; ++br) {
        const float* in_w   = (const float*)d_in[1 + 10 * br + 0];
        const float* conv_w = (const float*)d_in[1 + 10 * br + 1];
        const float* conv_b = (const float*)d_in[1 + 10 * br + 2];
        const float* x_w    = (const float*)d_in[1 + 10 * br + 3];
        const float* dt_w   = (const float*)d_in[1 + 10 * br + 4];
        const float* dt_b   = (const float*)d_in[1 + 10 * br + 5];
        const float* A_log  = (const float*)d_in[1 + 10 * br + 6];
        const float* Dp     = (const float*)d_in[1 + 10 * br + 7];
        const float* out_w  = (const float*)d_in[1 + 10 * br + 8];
        const float* norm_w = (const float*)d_in[1 + 10 * br + 9];
        const int S = br ? 32 : 16;
        const int Mdbc = DTR + 2 * S;    // 80 / 112
        float* xbuf = br ? xl : xs;

        for (int i = 0; i < NL; ++i) {
            rmsnorm_kernel<<<NTOK, 256, 0, stream>>>(xbuf, norm_w + i * DM, xn);

            dim3 g1(NTOK / 64, (2 * DI) / 64);
            gemm_nt<0, false, false><<<g1, 256, 0, stream>>>(
                xn, DM, in_w + (size_t)i * 2 * DI * DM, nullptr,
                xz, 2 * DI, 2 * DI, DM);

            if (br == 0)
                conv_silu_kernel<3><<<(NTOK * DI) / 256, 256, 0, stream>>>(
                    xz, conv_w + i * DI * 3, conv_b + i * DI, xi);
            else
                conv_silu_kernel<9><<<(NTOK * DI) / 256, 256, 0, stream>>>(
                    xz, conv_w + i * DI * 9, conv_b + i * DI, xi);

            dim3 g2(NTOK / 64, (Mdbc + 63) / 64);
            gemm_nt<0, false, false><<<g2, 256, 0, stream>>>(
                xi, DI, x_w + (size_t)i * Mdbc * DI, nullptr,
                dbc, 128, Mdbc, DI);

            dim3 g3(NTOK / 64, DI / 64);
            gemm_nt<1, true, false><<<g3, 256, 0, stream>>>(
                dbc, 128, dt_w + (size_t)i * DI * DTR, dt_b + i * DI,
                delta, DI, DI, DTR);

            // ---- chunked scan ----
            // chunk-state buffers live in xn (dead until next rmsnorm):
            //   dec  : B*DI*S*NC floats   hstart/hfin : B*DI*S*NC floats
            // S=16,NC=16 and S=32,NC=8 both give 786432 floats each; xn holds
            // 1572864 floats -> exactly fits both.
            float* dec  = xn;
            float* hfin = xn + 786432;
            if (br == 0) {
                scan_phase1<16, 16><<<786432 / 256, 256, 0, stream>>>(
                    delta, dbc, xi, xz, A_log + (size_t)i * DI * 16, dec, hfin);
                scan_phase2<16, 16><<<(B_ * DI * 16) / 256, 256, 0, stream>>>(
                    dec, hfin);
                scan_phase3<16, 16><<<786432 / 256, 256, 0, stream>>>(
                    delta, dbc, xi, xz, A_log + (size_t)i * DI * 16,
                    Dp + i * DI, hfin);
            } else {
                scan_phase1<32, 8><<<786432 / 256, 256, 0, stream>>>(
                    delta, dbc, xi, xz, A_log + (size_t)i * DI * 32, dec, hfin);
                scan_phase2<32, 8><<<(B_ * DI * 32) / 256, 256, 0, stream>>>(
                    dec, hfin);
                scan_phase3<32, 8><<<786432 / 256, 256, 0, stream>>>(
                    delta, dbc, xi, xz, A_log + (size_t)i * DI * 32,
                    Dp + i * DI, hfin);
            }

            dim3 g4(NTOK / 64, DM / 64);
            gemm_nt<0, false, true><<<g4, 256, 0, stream>>>(
                xi, DI, out_w + (size_t)i * DM * DI, nullptr,
                xbuf, DM, DM, DI);
        }
    }

    // ---- fusion head ----
    float* xc = xz;
    float* gp = xz + (size_t)NTOK * 2 * DM;
    pack_xc_kernel<<<(NTOK * 2 * DM) / 256, 256, 0, stream>>>(xs, xl, xc);

    dim3 g5(NTOK / 64, DM / 64);
    gemm_nt<0, true, false><<<g5, 256, 0, stream>>>(
        xc, 2 * DM, gate_w, gate_b, gp, 2 * DM, DM, 2 * DM);
    gemm_nt<0, true, false><<<g5, 256, 0, stream>>>(
        xc, 2 * DM, proj_w, proj_b, gp + DM, 2 * DM, DM, 2 * DM);

    fuse_ln_kernel<<<NTOK, 256, 0, stream>>>(
        xs, xl, gp, ln_w, ln_b, (float*)d_out);
}

// Round 3
// 1508.816 us; speedup vs baseline: 3.4631x; 2.3229x over previous
//
#include <hip/hip_runtime.h>
#include <math.h>

#define B_   2
#define L_   1024
#define DM   768
#define NL   2
#define DI   1536
#define DTR  48
#define NTOK (B_ * L_)   // 2048

typedef short    bf16x8 __attribute__((ext_vector_type(8)));
typedef float    f32x4  __attribute__((ext_vector_type(4)));

__device__ __forceinline__ ushort f2bf_rne(float f) {
    unsigned u = __builtin_bit_cast(unsigned, f);
    unsigned r = u + 0x7FFFu + ((u >> 16) & 1u);
    return (ushort)(r >> 16);
}

// ---------------------------------------------------------------------------
__device__ __forceinline__ void blockReduce2(float& a, float& b) {
    #pragma unroll
    for (int off = 32; off; off >>= 1) {
        a += __shfl_down(a, off);
        b += __shfl_down(b, off);
    }
    __shared__ float sa[4], sb[4];
    int lane = threadIdx.x & 63, w = threadIdx.x >> 6;
    if (lane == 0) { sa[w] = a; sb[w] = b; }
    __syncthreads();
    if (threadIdx.x == 0) {
        float ta = 0.f, tb = 0.f;
        #pragma unroll
        for (int i = 0; i < 4; i++) { ta += sa[i]; tb += sb[i]; }
        sa[0] = ta; sb[0] = tb;
    }
    __syncthreads();
    a = sa[0]; b = sb[0];
}

// ---------------------------------------------------------------------------
__global__ void copy2_kernel(const float* __restrict__ x,
                             float* __restrict__ xs, float* __restrict__ xl) {
    int i = blockIdx.x * 256 + threadIdx.x;
    float v = x[i];
    xs[i] = v;
    xl[i] = v;
}

// fp32 -> bf16 bulk convert (n multiple of 4)
__global__ void f2bf_kernel(const float* __restrict__ in,
                            ushort* __restrict__ out, int n4) {
    int i = blockIdx.x * 256 + threadIdx.x;
    if (i < n4) {
        float4 v = ((const float4*)in)[i];
        ushort4 o;
        o.x = f2bf_rne(v.x); o.y = f2bf_rne(v.y);
        o.z = f2bf_rne(v.z); o.w = f2bf_rne(v.w);
        ((ushort4*)out)[i] = o;
    }
}

// ---------------------------------------------------------------------------
// RMSNorm -> bf16 output (one block per row)
// ---------------------------------------------------------------------------
__global__ void rmsnorm_bf16(const float* __restrict__ x,
                             const float* __restrict__ w,
                             ushort* __restrict__ out) {
    int n = blockIdx.x;
    const float* xr = x + (size_t)n * DM;
    float v[3];
    float ss = 0.f, dummy = 0.f;
    #pragma unroll
    for (int j = 0; j < 3; j++) {
        v[j] = xr[threadIdx.x + 256 * j];
        ss += v[j] * v[j];
    }
    blockReduce2(ss, dummy);
    float scale = rsqrtf(ss / DM + 1e-5f);
    #pragma unroll
    for (int j = 0; j < 3; j++) {
        int m = threadIdx.x + 256 * j;
        out[(size_t)n * DM + m] = f2bf_rne(v[j] * scale * w[m]);
    }
}

// ---------------------------------------------------------------------------
// bf16 MFMA GEMM, NT: C[n,m] = sum_k A[n,k] * W[m,k], fp32 out.
// 128x128 tile, 256 thr = 4 waves (2x2), each wave 64x64 via 4x4 mfma 16x16x32.
// Requires: rows %128==0 (2048 ok), Mout %128==0, K %32==0.
// ---------------------------------------------------------------------------
__device__ __forceinline__ int ldsIdx(int row, int kg) {
    return row * 32 + ((kg ^ ((row >> 1) & 3)) << 3);   // ushort units
}

template<bool BIAS, bool RES>
__global__ __launch_bounds__(256) void gemm_bf16_mfma(
        const ushort* __restrict__ A,   // [*,K] bf16
        const ushort* __restrict__ W,   // [Mout,K] bf16
        const float* __restrict__ bias,
        float* __restrict__ C, int ldc, int K) {
    __shared__ ushort As[128 * 32];
    __shared__ ushort Bs[128 * 32];
    const int tid  = threadIdx.x;
    const int lane = tid & 63;
    const int wid  = tid >> 6;
    const int wr   = wid >> 1, wc = wid & 1;
    const int n0 = blockIdx.x * 128, m0 = blockIdx.y * 128;

    const int srow = tid >> 2;
    const int skg  = tid & 3;
    const ushort* ag = A + (size_t)(n0 + srow) * K + skg * 8;
    const ushort* wg = W + (size_t)(m0 + srow) * K + skg * 8;
    const int w0 = ldsIdx(srow,      skg);
    const int w1 = ldsIdx(srow + 64, skg);
    const int frow = lane & 15;
    const int fkg  = lane >> 4;

    f32x4 acc[4][4] = {};

    for (int k0 = 0; k0 < K; k0 += 32) {
        bf16x8 a0 = *(const bf16x8*)(ag + k0);
        bf16x8 a1 = *(const bf16x8*)(ag + (size_t)64 * K + k0);
        bf16x8 b0 = *(const bf16x8*)(wg + k0);
        bf16x8 b1 = *(const bf16x8*)(wg + (size_t)64 * K + k0);
        __syncthreads();
        *(bf16x8*)&As[w0] = a0;  *(bf16x8*)&As[w1] = a1;
        *(bf16x8*)&Bs[w0] = b0;  *(bf16x8*)&Bs[w1] = b1;
        __syncthreads();
        bf16x8 af[4], bfr[4];
        #pragma unroll
        for (int i = 0; i < 4; i++) {
            af[i]  = *(const bf16x8*)&As[ldsIdx(wr * 64 + i * 16 + frow, fkg)];
            bfr[i] = *(const bf16x8*)&Bs[ldsIdx(wc * 64 + i * 16 + frow, fkg)];
        }
        #pragma unroll
        for (int i = 0; i < 4; i++)
            #pragma unroll
            for (int j = 0; j < 4; j++)
                acc[i][j] = __builtin_amdgcn_mfma_f32_16x16x32_bf16(
                    af[i], bfr[j], acc[i][j], 0, 0, 0);
    }

    #pragma unroll
    for (int i = 0; i < 4; i++) {
        int row = n0 + wr * 64 + i * 16 + (lane >> 4) * 4;
        #pragma unroll
        for (int j = 0; j < 4; j++) {
            int col = m0 + wc * 64 + j * 16 + (lane & 15);
            float bv = BIAS ? bias[col] : 0.f;
            #pragma unroll
            for (int r = 0; r < 4; r++) {
                float v = acc[i][j][r] + bv;
                float* cp = C + (size_t)(row + r) * ldc + col;
                if (RES) v += *cp;
                *cp = v;
            }
        }
    }
}

// ---------------------------------------------------------------------------
// fp32 vector GEMM (kept for the small x_w / dt_w matmuls)
// ---------------------------------------------------------------------------
template<int ACT, bool BIAS, bool RES>
__global__ __launch_bounds__(256) void gemm_nt(
        const float* __restrict__ A, int lda,
        const float* __restrict__ W,
        const float* __restrict__ bias,
        float* __restrict__ C, int ldc,
        int M, int K) {
    __shared__ float As[16][65];
    __shared__ float Bs[16][65];
    int n0 = blockIdx.x * 64;
    int m0 = blockIdx.y * 64;
    int tid = threadIdx.x;
    int tx = tid & 15, ty = tid >> 4;
    int arow = tid >> 2;
    int kq = (tid & 3) * 4;
    float acc[4][4] = {};

    for (int kt = 0; kt < K; kt += 16) {
        {
            const float4 v = *(const float4*)(A + (size_t)(n0 + arow) * lda + kt + kq);
            As[kq + 0][arow] = v.x; As[kq + 1][arow] = v.y;
            As[kq + 2][arow] = v.z; As[kq + 3][arow] = v.w;
        }
        {
            int m = m0 + arow;
            float4 v = make_float4(0.f, 0.f, 0.f, 0.f);
            if (m < M) v = *(const float4*)(W + (size_t)m * K + kt + kq);
            Bs[kq + 0][arow] = v.x; Bs[kq + 1][arow] = v.y;
            Bs[kq + 2][arow] = v.z; Bs[kq + 3][arow] = v.w;
        }
        __syncthreads();
        #pragma unroll
        for (int k = 0; k < 16; k++) {
            float av[4], bv[4];
            #pragma unroll
            for (int i = 0; i < 4; i++) av[i] = As[k][ty * 4 + i];
            #pragma unroll
            for (int j = 0; j < 4; j++) bv[j] = Bs[k][tx * 4 + j];
            #pragma unroll
            for (int i = 0; i < 4; i++)
                #pragma unroll
                for (int j = 0; j < 4; j++)
                    acc[i][j] += av[i] * bv[j];
        }
        __syncthreads();
    }

    #pragma unroll
    for (int i = 0; i < 4; i++) {
        int row = n0 + ty * 4 + i;
        #pragma unroll
        for (int j = 0; j < 4; j++) {
            int col = m0 + tx * 4 + j;
            if (col < M) {
                float v = acc[i][j];
                if (BIAS) v += bias[col];
                if (ACT == 1) v = (v > 20.f) ? v : log1pf(__expf(v));
                float* cp = C + (size_t)row * ldc + col;
                if (RES) v += *cp;
                *cp = v;
            }
        }
    }
}

// ---------------------------------------------------------------------------
// Depthwise causal conv along L (+bias, +SiLU) -> xi fp32
// ---------------------------------------------------------------------------
template<int K>
__global__ void conv_silu_kernel(const float* __restrict__ xz,
                                 const float* __restrict__ cw,
                                 const float* __restrict__ cb,
                                 float* __restrict__ xi) {
    int idx = blockIdx.x * 256 + threadIdx.x;
    int c = idx % DI;
    int n = idx / DI;
    int l = n % L_;
    float acc = cb[c];
    #pragma unroll
    for (int k = 0; k < K; k++) {
        int lp = l - (K - 1) + k;
        if (lp >= 0)
            acc += xz[(size_t)(n - (K - 1) + k) * (2 * DI) + c] * cw[c * K + k];
    }
    xi[(size_t)n * DI + c] = acc / (1.f + __expf(-acc));
}

// ---------------------------------------------------------------------------
// Chunked selective scan, d-parallel layout.
// State layout: dec/hfin[ ((b*NC + c)*S + s)*DI + d ]
// phase1: block = (d-range 256, chunk c, batch b); h[S],a[S] in regs.
// ---------------------------------------------------------------------------
template<int S, int NC>
__global__ __launch_bounds__(256) void scan_p1(
        float* __restrict__ delta,        // in delta / out cumd
        const float* __restrict__ dbc,
        const float* __restrict__ xi,
        float* __restrict__ yloc,         // xz base (stride 2*DI)
        const float* __restrict__ A_log,
        float* __restrict__ dec,
        float* __restrict__ hfin) {
    const int CL = L_ / NC;
    const int d = blockIdx.x * 256 + threadIdx.x;
    const int c = blockIdx.y;
    const int b = blockIdx.z;
    float a[S], h[S];
    #pragma unroll
    for (int s = 0; s < S; s++) {
        a[s] = -__expf(A_log[d * S + s]);
        h[s] = 0.f;
    }
    float dsum = 0.f;
    __shared__ float bcs[16][128];
    const size_t row0 = (size_t)b * L_ + (size_t)c * CL;

    for (int t0 = 0; t0 < CL; t0 += 16) {
        __syncthreads();
        {
            const float4* src = (const float4*)(dbc + (row0 + t0) * 128);
            float4* dst = (float4*)&bcs[0][0];
            dst[threadIdx.x]       = src[threadIdx.x];
            dst[threadIdx.x + 256] = src[threadIdx.x + 256];
        }
        __syncthreads();
        #pragma unroll 1
        for (int tt = 0; tt < 16; ++tt) {
            size_t row = row0 + t0 + tt;
            float dlt = delta[row * DI + d];
            float x   = xi[row * DI + d];
            dsum += dlt;
            float dx = dlt * x;
            float p = 0.f;
            #pragma unroll
            for (int s = 0; s < S; s++) {
                float e = __expf(dlt * a[s]);
                h[s] = e * h[s] + dx * bcs[tt][DTR + s];
                p += h[s] * bcs[tt][DTR + S + s];
            }
            yloc[row * (2 * DI) + d] = p;
            delta[row * DI + d] = dsum;
        }
    }
    #pragma unroll
    for (int s = 0; s < S; s++) {
        size_t idx = (((size_t)b * NC + c) * S + s) * DI + d;
        dec[idx]  = __expf(a[s] * dsum);
        hfin[idx] = h[s];
    }
}

// phase2: sequential over chunks; hfin becomes h_start. thread per (b,s,d).
template<int S, int NC>
__global__ void scan_p2(const float* __restrict__ dec,
                        float* __restrict__ hfin) {
    int gid = blockIdx.x * 256 + threadIdx.x;   // (b*S+s)*DI + d
    int d = gid % DI;
    int s = (gid / DI) % S;
    int b = gid / (DI * S);
    float run = 0.f;
    #pragma unroll
    for (int c = 0; c < NC; ++c) {
        size_t idx = (((size_t)b * NC + c) * S + s) * DI + d;
        float dc = dec[idx];
        float hf = hfin[idx];
        hfin[idx] = run;
        run = dc * run + hf;
    }
}

// phase3: y = yloc + C.(exp(a*cumd)*h_start) + x*D, *= silu(z) -> bf16 u.
// block = (d-range 256, 16-token tile, batch b)
template<int S, int NC>
__global__ __launch_bounds__(256) void scan_p3(
        const float* __restrict__ cumd,
        const float* __restrict__ dbc,
        const float* __restrict__ xi,
        const float* __restrict__ xz,       // yloc + z
        const float* __restrict__ A_log,
        const float* __restrict__ Dp,
        const float* __restrict__ hstart,
        ushort* __restrict__ u_bf) {
    const int CL = L_ / NC;
    const int d  = blockIdx.x * 256 + threadIdx.x;
    const int t0 = blockIdx.y * 16;
    const int b  = blockIdx.z;
    const int c  = t0 / CL;
    float a[S], hs[S];
    #pragma unroll
    for (int s = 0; s < S; s++) {
        a[s]  = -__expf(A_log[d * S + s]);
        hs[s] = hstart[(((size_t)b * NC + c) * S + s) * DI + d];
    }
    float Dv = Dp[d];
    __shared__ float bcs[16][128];
    {
        const float4* src = (const float4*)(dbc + ((size_t)b * L_ + t0) * 128);
        float4* dst = (float4*)&bcs[0][0];
        dst[threadIdx.x]       = src[threadIdx.x];
        dst[threadIdx.x + 256] = src[threadIdx.x + 256];
    }
    __syncthreads();
    #pragma unroll 1
    for (int tt = 0; tt < 16; ++tt) {
        size_t row = (size_t)b * L_ + t0 + tt;
        float cd = cumd[row * DI + d];
        float p = 0.f;
        #pragma unroll
        for (int s = 0; s < S; s++)
            p += __expf(a[s] * cd) * hs[s] * bcs[tt][DTR + S + s];
        float x  = xi[row * DI + d];
        float yl = xz[row * (2 * DI) + d];
        float z  = xz[row * (2 * DI) + DI + d];
        float y  = yl + p + x * Dv;
        float u  = y * (z / (1.f + __expf(-z)));
        u_bf[row * DI + d] = f2bf_rne(u);
    }
}

// ---------------------------------------------------------------------------
__global__ void pack_xc_bf16(const float* __restrict__ xs,
                             const float* __restrict__ xl,
                             ushort* __restrict__ xc) {
    int idx = blockIdx.x * 256 + threadIdx.x;
    int n = idx / (2 * DM);
    int m = idx % (2 * DM);
    float v = (m < DM) ? xs[(size_t)n * DM + m] : xl[(size_t)n * DM + m - DM];
    xc[idx] = f2bf_rne(v);
}

// ---------------------------------------------------------------------------
__global__ void fuse_ln_kernel(const float* __restrict__ xs,
                               const float* __restrict__ xl,
                               const float* __restrict__ gp,
                               const float* __restrict__ ln_w,
                               const float* __restrict__ ln_b,
                               float* __restrict__ out) {
    int n = blockIdx.x;
    float v[3];
    float sum = 0.f, sumsq = 0.f;
    #pragma unroll
    for (int j = 0; j < 3; j++) {
        int m = threadIdx.x + 256 * j;
        float g    = gp[(size_t)n * (2 * DM) + m];
        float gate = 1.f / (1.f + __expf(-g));
        float p    = gp[(size_t)n * (2 * DM) + DM + m];
        float val  = gate * xs[(size_t)n * DM + m]
                   + (1.f - gate) * xl[(size_t)n * DM + m] + p;
        v[j] = val;
        sum += val; sumsq += val * val;
    }
    blockReduce2(sum, sumsq);
    float mean = sum / DM;
    float var  = sumsq / DM - mean * mean;
    float inv  = rsqrtf(var + 1e-5f);
    #pragma unroll
    for (int j = 0; j < 3; j++) {
        int m = threadIdx.x + 256 * j;
        out[(size_t)n * DM + m] = (v[j] - mean) * inv * ln_w[m] + ln_b[m];
    }
}

// ---------------------------------------------------------------------------
extern "C" void kernel_launch(void* const* d_in, const int* in_sizes, int n_in,
                              void* d_out, int out_size, void* d_ws, size_t ws_size,
                              hipStream_t stream) {
    const float* x      = (const float*)d_in[0];
    const float* gate_w = (const float*)d_in[21];
    const float* gate_b = (const float*)d_in[22];
    const float* proj_w = (const float*)d_in[23];
    const float* proj_b = (const float*)d_in[24];
    const float* ln_w   = (const float*)d_in[25];
    const float* ln_b   = (const float*)d_in[26];

    float* ws = (float*)d_ws;
    size_t off = 0;
    float* xs    = ws + off; off += (size_t)NTOK * DM;       // 1.57M f
    float* xl    = ws + off; off += (size_t)NTOK * DM;
    float* xn    = ws + off; off += (size_t)NTOK * DM;       // wbuf + scan state
    float* xz    = ws + off; off += (size_t)NTOK * 2 * DI;   // 6.29M f
    float* xi    = ws + off; off += (size_t)NTOK * DI;
    float* dbc   = ws + off; off += (size_t)NTOK * 128;
    float* delta = ws + off; off += (size_t)NTOK * DI;
    ushort* xn_bf = (ushort*)(ws + off); off += (size_t)NTOK * DM / 2;   // bf16
    ushort* xi_bf = (ushort*)(ws + off); off += (size_t)NTOK * DI / 2;   // bf16
    // total ~19.9M floats = 79.7 MB

    ushort* wbuf = (ushort*)xn;          // weight bf16 scratch (aliases xn)
    float*  dec  = xn;                   // scan chunk state (aliases xn)
    float*  hfin = xn + 786432;          // both uses temporally disjoint

    copy2_kernel<<<(NTOK * DM) / 256, 256, 0, stream>>>(x, xs, xl);

    for (int br = 0; br < 2; ++br) {
        const float* in_w   = (const float*)d_in[1 + 10 * br + 0];
        const float* conv_w = (const float*)d_in[1 + 10 * br + 1];
        const float* conv_b = (const float*)d_in[1 + 10 * br + 2];
        const float* x_w    = (const float*)d_in[1 + 10 * br + 3];
        const float* dt_w   = (const float*)d_in[1 + 10 * br + 4];
        const float* dt_b   = (const float*)d_in[1 + 10 * br + 5];
        const float* A_log  = (const float*)d_in[1 + 10 * br + 6];
        const float* Dp     = (const float*)d_in[1 + 10 * br + 7];
        const float* out_w  = (const float*)d_in[1 + 10 * br + 8];
        const float* norm_w = (const float*)d_in[1 + 10 * br + 9];
        const int S = br ? 32 : 16;
        const int Mdbc = DTR + 2 * S;    // 80 / 112
        float* xbuf = br ? xl : xs;

        for (int i = 0; i < NL; ++i) {
            rmsnorm_bf16<<<NTOK, 256, 0, stream>>>(xbuf, norm_w + i * DM, xn_bf);

            // convert in_w[i] (3072x768) to bf16 scratch, then MFMA GEMM
            f2bf_kernel<<<(2 * DI * DM / 4 + 255) / 256, 256, 0, stream>>>(
                in_w + (size_t)i * 2 * DI * DM, wbuf, 2 * DI * DM / 4);
            gemm_bf16_mfma<false, false><<<dim3(NTOK / 128, 2 * DI / 128), 256, 0, stream>>>(
                xn_bf, wbuf, nullptr, xz, 2 * DI, DM);

            if (br == 0)
                conv_silu_kernel<3><<<(NTOK * DI) / 256, 256, 0, stream>>>(
                    xz, conv_w + i * DI * 3, conv_b + i * DI, xi);
            else
                conv_silu_kernel<9><<<(NTOK * DI) / 256, 256, 0, stream>>>(
                    xz, conv_w + i * DI * 9, conv_b + i * DI, xi);

            dim3 g2(NTOK / 64, (Mdbc + 63) / 64);
            gemm_nt<0, false, false><<<g2, 256, 0, stream>>>(
                xi, DI, x_w + (size_t)i * Mdbc * DI, nullptr,
                dbc, 128, Mdbc, DI);

            dim3 g3(NTOK / 64, DI / 64);
            gemm_nt<1, true, false><<<g3, 256, 0, stream>>>(
                dbc, 128, dt_w + (size_t)i * DI * DTR, dt_b + i * DI,
                delta, DI, DI, DTR);

            // ---- chunked scan (d-parallel) ----
            if (br == 0) {
                scan_p1<16, 16><<<dim3(DI / 256, 16, B_), 256, 0, stream>>>(
                    delta, dbc, xi, xz, A_log + (size_t)i * DI * 16, dec, hfin);
                scan_p2<16, 16><<<(B_ * 16 * DI) / 256, 256, 0, stream>>>(dec, hfin);
                scan_p3<16, 16><<<dim3(DI / 256, L_ / 16, B_), 256, 0, stream>>>(
                    delta, dbc, xi, xz, A_log + (size_t)i * DI * 16,
                    Dp + i * DI, hfin, xi_bf);
            } else {
                scan_p1<32, 8><<<dim3(DI / 256, 8, B_), 256, 0, stream>>>(
                    delta, dbc, xi, xz, A_log + (size_t)i * DI * 32, dec, hfin);
                scan_p2<32, 8><<<(B_ * 32 * DI) / 256, 256, 0, stream>>>(dec, hfin);
                scan_p3<32, 8><<<dim3(DI / 256, L_ / 16, B_), 256, 0, stream>>>(
                    delta, dbc, xi, xz, A_log + (size_t)i * DI * 32,
                    Dp + i * DI, hfin, xi_bf);
            }

            // out_w[i] (768x1536) -> bf16, MFMA GEMM with residual add
            f2bf_kernel<<<(DM * DI / 4 + 255) / 256, 256, 0, stream>>>(
                out_w + (size_t)i * DM * DI, wbuf, DM * DI / 4);
            gemm_bf16_mfma<false, true><<<dim3(NTOK / 128, DM / 128), 256, 0, stream>>>(
                xi_bf, wbuf, nullptr, xbuf, DM, DI);
        }
    }

    // ---- fusion head ----
    ushort* xc_bf = xi_bf;                       // xi_bf free now
    float* gp = xz;                              // reuse xz region
    pack_xc_bf16<<<(NTOK * 2 * DM) / 256, 256, 0, stream>>>(xs, xl, xc_bf);

    f2bf_kernel<<<(DM * 2 * DM / 4 + 255) / 256, 256, 0, stream>>>(
        gate_w, wbuf, DM * 2 * DM / 4);
    gemm_bf16_mfma<true, false><<<dim3(NTOK / 128, DM / 128), 256, 0, stream>>>(
        xc_bf, wbuf, gate_b, gp, 2 * DM, 2 * DM);
    f2bf_kernel<<<(DM * 2 * DM / 4 + 255) / 256, 256, 0, stream>>>(
        proj_w, wbuf, DM * 2 * DM / 4);
    gemm_bf16_mfma<true, false><<<dim3(NTOK / 128, DM / 128), 256, 0, stream>>>(
        xc_bf, wbuf, proj_b, gp + DM, 2 * DM, 2 * DM);

    fuse_ln_kernel<<<NTOK, 256, 0, stream>>>(
        xs, xl, gp, ln_w, ln_b, (float*)d_out);
}

// Round 4
// 900.293 us; speedup vs baseline: 5.8039x; 1.6759x over previous
//
#include <hip/hip_runtime.h>
#include <math.h>

#define B_   2
#define L_   1024
#define DM   768
#define NL   2
#define DI   1536
#define DTR  48
#define NTOK (B_ * L_)   // 2048
#define NCC  32          // scan chunks (both branches), CL = 32

typedef short    bf16x8 __attribute__((ext_vector_type(8)));
typedef float    f32x4  __attribute__((ext_vector_type(4)));

__device__ __forceinline__ ushort f2bf_rne(float f) {
    unsigned u = __builtin_bit_cast(unsigned, f);
    unsigned r = u + 0x7FFFu + ((u >> 16) & 1u);
    return (ushort)(r >> 16);
}
__device__ __forceinline__ float bf2f(ushort u) {
    return __builtin_bit_cast(float, (unsigned)u << 16);
}

// ---------------------------------------------------------------------------
__device__ __forceinline__ void blockReduce2(float& a, float& b) {
    #pragma unroll
    for (int off = 32; off; off >>= 1) {
        a += __shfl_down(a, off);
        b += __shfl_down(b, off);
    }
    __shared__ float sa[4], sb[4];
    int lane = threadIdx.x & 63, w = threadIdx.x >> 6;
    if (lane == 0) { sa[w] = a; sb[w] = b; }
    __syncthreads();
    if (threadIdx.x == 0) {
        float ta = 0.f, tb = 0.f;
        #pragma unroll
        for (int i = 0; i < 4; i++) { ta += sa[i]; tb += sb[i]; }
        sa[0] = ta; sb[0] = tb;
    }
    __syncthreads();
    a = sa[0]; b = sb[0];
}

// ---------------------------------------------------------------------------
__global__ void copy2_kernel(const float* __restrict__ x,
                             float* __restrict__ xs, float* __restrict__ xl) {
    int i = blockIdx.x * 256 + threadIdx.x;
    float v = x[i];
    xs[i] = v;
    xl[i] = v;
}

// fp32 -> bf16 bulk convert (n4 = count/4)
__global__ void f2bf_kernel(const float* __restrict__ in,
                            ushort* __restrict__ out, int n4) {
    int i = blockIdx.x * 256 + threadIdx.x;
    if (i < n4) {
        float4 v = ((const float4*)in)[i];
        ushort4 o;
        o.x = f2bf_rne(v.x); o.y = f2bf_rne(v.y);
        o.z = f2bf_rne(v.z); o.w = f2bf_rne(v.w);
        ((ushort4*)out)[i] = o;
    }
}

// ---------------------------------------------------------------------------
__global__ void rmsnorm_bf16(const float* __restrict__ x,
                             const float* __restrict__ w,
                             ushort* __restrict__ out) {
    int n = blockIdx.x;
    const float* xr = x + (size_t)n * DM;
    float v[3];
    float ss = 0.f, dummy = 0.f;
    #pragma unroll
    for (int j = 0; j < 3; j++) {
        v[j] = xr[threadIdx.x + 256 * j];
        ss += v[j] * v[j];
    }
    blockReduce2(ss, dummy);
    float scale = rsqrtf(ss / DM + 1e-5f);
    #pragma unroll
    for (int j = 0; j < 3; j++) {
        int m = threadIdx.x + 256 * j;
        out[(size_t)n * DM + m] = f2bf_rne(v[j] * scale * w[m]);
    }
}

// ---------------------------------------------------------------------------
// XOR-swizzled LDS index (ushort units, 32 per row)
// ---------------------------------------------------------------------------
__device__ __forceinline__ int ldsIdx(int row, int kg) {
    return row * 32 + ((kg ^ ((row >> 1) & 3)) << 3);
}

// ---------------------------------------------------------------------------
// bf16 MFMA GEMM, 128x128 tile, 4 waves (2x2), NT layout.
// ---------------------------------------------------------------------------
template<bool BIAS, bool RES>
__global__ __launch_bounds__(256) void gemm_bf16_mfma(
        const ushort* __restrict__ A,
        const ushort* __restrict__ W,
        const float* __restrict__ bias,
        float* __restrict__ C, int ldc, int K) {
    __shared__ ushort As[128 * 32];
    __shared__ ushort Bs[128 * 32];
    const int tid  = threadIdx.x;
    const int lane = tid & 63;
    const int wid  = tid >> 6;
    const int wr   = wid >> 1, wc = wid & 1;
    const int n0 = blockIdx.x * 128, m0 = blockIdx.y * 128;

    const int srow = tid >> 2;
    const int skg  = tid & 3;
    const ushort* ag = A + (size_t)(n0 + srow) * K + skg * 8;
    const ushort* wg = W + (size_t)(m0 + srow) * K + skg * 8;
    const int w0 = ldsIdx(srow,      skg);
    const int w1 = ldsIdx(srow + 64, skg);
    const int frow = lane & 15;
    const int fkg  = lane >> 4;

    f32x4 acc[4][4] = {};

    for (int k0 = 0; k0 < K; k0 += 32) {
        bf16x8 a0 = *(const bf16x8*)(ag + k0);
        bf16x8 a1 = *(const bf16x8*)(ag + (size_t)64 * K + k0);
        bf16x8 b0 = *(const bf16x8*)(wg + k0);
        bf16x8 b1 = *(const bf16x8*)(wg + (size_t)64 * K + k0);
        __syncthreads();
        *(bf16x8*)&As[w0] = a0;  *(bf16x8*)&As[w1] = a1;
        *(bf16x8*)&Bs[w0] = b0;  *(bf16x8*)&Bs[w1] = b1;
        __syncthreads();
        bf16x8 af[4], bfr[4];
        #pragma unroll
        for (int i = 0; i < 4; i++) {
            af[i]  = *(const bf16x8*)&As[ldsIdx(wr * 64 + i * 16 + frow, fkg)];
            bfr[i] = *(const bf16x8*)&Bs[ldsIdx(wc * 64 + i * 16 + frow, fkg)];
        }
        #pragma unroll
        for (int i = 0; i < 4; i++)
            #pragma unroll
            for (int j = 0; j < 4; j++)
                acc[i][j] = __builtin_amdgcn_mfma_f32_16x16x32_bf16(
                    af[i], bfr[j], acc[i][j], 0, 0, 0);
    }

    #pragma unroll
    for (int i = 0; i < 4; i++) {
        int row = n0 + wr * 64 + i * 16 + (lane >> 4) * 4;
        #pragma unroll
        for (int j = 0; j < 4; j++) {
            int col = m0 + wc * 64 + j * 16 + (lane & 15);
            float bv = BIAS ? bias[col] : 0.f;
            #pragma unroll
            for (int r = 0; r < 4; r++) {
                float v = acc[i][j][r] + bv;
                float* cp = C + (size_t)(row + r) * ldc + col;
                if (RES) v += *cp;
                *cp = v;
            }
        }
    }
}

// ---------------------------------------------------------------------------
// bf16 MFMA GEMM, 128x64 tile, 4 waves (4x1) — better grid for M=768.
// ---------------------------------------------------------------------------
template<bool BIAS, bool RES>
__global__ __launch_bounds__(256) void gemm_bf16_mfma_64(
        const ushort* __restrict__ A,
        const ushort* __restrict__ W,
        const float* __restrict__ bias,
        float* __restrict__ C, int ldc, int K) {
    __shared__ ushort As[128 * 32];
    __shared__ ushort Bs[64 * 32];
    const int tid  = threadIdx.x;
    const int lane = tid & 63;
    const int wid  = tid >> 6;
    const int n0 = blockIdx.x * 128, m0 = blockIdx.y * 64;

    const int srow = tid >> 2;           // 0..63
    const int skg  = tid & 3;
    const ushort* ag = A + (size_t)(n0 + srow) * K + skg * 8;
    const ushort* wg = W + (size_t)(m0 + srow) * K + skg * 8;
    const int w0 = ldsIdx(srow,      skg);
    const int w1 = ldsIdx(srow + 64, skg);
    const int frow = lane & 15;
    const int fkg  = lane >> 4;

    f32x4 acc[2][4] = {};

    for (int k0 = 0; k0 < K; k0 += 32) {
        bf16x8 a0 = *(const bf16x8*)(ag + k0);
        bf16x8 a1 = *(const bf16x8*)(ag + (size_t)64 * K + k0);
        bf16x8 b0 = *(const bf16x8*)(wg + k0);
        __syncthreads();
        *(bf16x8*)&As[w0] = a0;  *(bf16x8*)&As[w1] = a1;
        *(bf16x8*)&Bs[w0] = b0;
        __syncthreads();
        bf16x8 af[2], bfr[4];
        #pragma unroll
        for (int i = 0; i < 2; i++)
            af[i] = *(const bf16x8*)&As[ldsIdx(wid * 32 + i * 16 + frow, fkg)];
        #pragma unroll
        for (int j = 0; j < 4; j++)
            bfr[j] = *(const bf16x8*)&Bs[ldsIdx(j * 16 + frow, fkg)];
        #pragma unroll
        for (int i = 0; i < 2; i++)
            #pragma unroll
            for (int j = 0; j < 4; j++)
                acc[i][j] = __builtin_amdgcn_mfma_f32_16x16x32_bf16(
                    af[i], bfr[j], acc[i][j], 0, 0, 0);
    }

    #pragma unroll
    for (int i = 0; i < 2; i++) {
        int row = n0 + wid * 32 + i * 16 + (lane >> 4) * 4;
        #pragma unroll
        for (int j = 0; j < 4; j++) {
            int col = m0 + j * 16 + (lane & 15);
            float bv = BIAS ? bias[col] : 0.f;
            #pragma unroll
            for (int r = 0; r < 4; r++) {
                float v = acc[i][j][r] + bv;
                float* cp = C + (size_t)(row + r) * ldc + col;
                if (RES) v += *cp;
                *cp = v;
            }
        }
    }
}

// ---------------------------------------------------------------------------
// bf16 MFMA GEMM for x_w: M <= 128 (80/112), single block-column, M-guarded.
// C stride fixed 128.
// ---------------------------------------------------------------------------
__global__ __launch_bounds__(256) void gemm_bf16_mfma_xw(
        const ushort* __restrict__ A,
        const ushort* __restrict__ W,
        float* __restrict__ C, int M, int K) {
    __shared__ ushort As[128 * 32];
    __shared__ ushort Bs[128 * 32];
    const int tid  = threadIdx.x;
    const int lane = tid & 63;
    const int wid  = tid >> 6;
    const int wr   = wid >> 1, wc = wid & 1;
    const int n0 = blockIdx.x * 128;

    const int srow = tid >> 2;
    const int skg  = tid & 3;
    const ushort* ag = A + (size_t)(n0 + srow) * K + skg * 8;
    const ushort* wg = W + (size_t)srow * K + skg * 8;
    const int w0 = ldsIdx(srow,      skg);
    const int w1 = ldsIdx(srow + 64, skg);
    const int frow = lane & 15;
    const int fkg  = lane >> 4;
    const bool mok0 = srow < M;
    const bool mok1 = srow + 64 < M;

    f32x4 acc[4][4] = {};

    for (int k0 = 0; k0 < K; k0 += 32) {
        bf16x8 a0 = *(const bf16x8*)(ag + k0);
        bf16x8 a1 = *(const bf16x8*)(ag + (size_t)64 * K + k0);
        bf16x8 b0 = {}, b1 = {};
        if (mok0) b0 = *(const bf16x8*)(wg + k0);
        if (mok1) b1 = *(const bf16x8*)(wg + (size_t)64 * K + k0);
        __syncthreads();
        *(bf16x8*)&As[w0] = a0;  *(bf16x8*)&As[w1] = a1;
        *(bf16x8*)&Bs[w0] = b0;  *(bf16x8*)&Bs[w1] = b1;
        __syncthreads();
        bf16x8 af[4], bfr[4];
        #pragma unroll
        for (int i = 0; i < 4; i++) {
            af[i]  = *(const bf16x8*)&As[ldsIdx(wr * 64 + i * 16 + frow, fkg)];
            bfr[i] = *(const bf16x8*)&Bs[ldsIdx(wc * 64 + i * 16 + frow, fkg)];
        }
        #pragma unroll
        for (int i = 0; i < 4; i++)
            #pragma unroll
            for (int j = 0; j < 4; j++)
                acc[i][j] = __builtin_amdgcn_mfma_f32_16x16x32_bf16(
                    af[i], bfr[j], acc[i][j], 0, 0, 0);
    }

    #pragma unroll
    for (int i = 0; i < 4; i++) {
        int row = n0 + wr * 64 + i * 16 + (lane >> 4) * 4;
        #pragma unroll
        for (int j = 0; j < 4; j++) {
            int col = wc * 64 + j * 16 + (lane & 15);
            if (col < M) {
                #pragma unroll
                for (int r = 0; r < 4; r++)
                    C[(size_t)(row + r) * 128 + col] = acc[i][j][r];
            }
        }
    }
}

// ---------------------------------------------------------------------------
// fp32 vector GEMM (dt_w only: M=1536, K=48, softplus+bias)
// ---------------------------------------------------------------------------
template<int ACT, bool BIAS, bool RES>
__global__ __launch_bounds__(256) void gemm_nt(
        const float* __restrict__ A, int lda,
        const float* __restrict__ W,
        const float* __restrict__ bias,
        float* __restrict__ C, int ldc,
        int M, int K) {
    __shared__ float As[16][65];
    __shared__ float Bs[16][65];
    int n0 = blockIdx.x * 64;
    int m0 = blockIdx.y * 64;
    int tid = threadIdx.x;
    int tx = tid & 15, ty = tid >> 4;
    int arow = tid >> 2;
    int kq = (tid & 3) * 4;
    float acc[4][4] = {};

    for (int kt = 0; kt < K; kt += 16) {
        {
            const float4 v = *(const float4*)(A + (size_t)(n0 + arow) * lda + kt + kq);
            As[kq + 0][arow] = v.x; As[kq + 1][arow] = v.y;
            As[kq + 2][arow] = v.z; As[kq + 3][arow] = v.w;
        }
        {
            int m = m0 + arow;
            float4 v = make_float4(0.f, 0.f, 0.f, 0.f);
            if (m < M) v = *(const float4*)(W + (size_t)m * K + kt + kq);
            Bs[kq + 0][arow] = v.x; Bs[kq + 1][arow] = v.y;
            Bs[kq + 2][arow] = v.z; Bs[kq + 3][arow] = v.w;
        }
        __syncthreads();
        #pragma unroll
        for (int k = 0; k < 16; k++) {
            float av[4], bv[4];
            #pragma unroll
            for (int i = 0; i < 4; i++) av[i] = As[k][ty * 4 + i];
            #pragma unroll
            for (int j = 0; j < 4; j++) bv[j] = Bs[k][tx * 4 + j];
            #pragma unroll
            for (int i = 0; i < 4; i++)
                #pragma unroll
                for (int j = 0; j < 4; j++)
                    acc[i][j] += av[i] * bv[j];
        }
        __syncthreads();
    }

    #pragma unroll
    for (int i = 0; i < 4; i++) {
        int row = n0 + ty * 4 + i;
        #pragma unroll
        for (int j = 0; j < 4; j++) {
            int col = m0 + tx * 4 + j;
            if (col < M) {
                float v = acc[i][j];
                if (BIAS) v += bias[col];
                if (ACT == 1) v = (v > 20.f) ? v : log1pf(__expf(v));
                float* cp = C + (size_t)row * ldc + col;
                if (RES) v += *cp;
                *cp = v;
            }
        }
    }
}

// ---------------------------------------------------------------------------
// Depthwise causal conv along L (+bias, +SiLU) -> bf16 xi
// ---------------------------------------------------------------------------
template<int K>
__global__ void conv_silu_kernel(const float* __restrict__ xz,
                                 const float* __restrict__ cw,
                                 const float* __restrict__ cb,
                                 ushort* __restrict__ xi) {
    int idx = blockIdx.x * 256 + threadIdx.x;
    int c = idx % DI;
    int n = idx / DI;
    int l = n % L_;
    float acc = cb[c];
    #pragma unroll
    for (int k = 0; k < K; k++) {
        int lp = l - (K - 1) + k;
        if (lp >= 0)
            acc += xz[(size_t)(n - (K - 1) + k) * (2 * DI) + c] * cw[c * K + k];
    }
    float v = acc / (1.f + __expf(-acc));
    xi[(size_t)n * DI + c] = f2bf_rne(v);
}

// ---------------------------------------------------------------------------
// Chunked selective scan, d-parallel. State: dec/hfin[((b*NC+c)*S+s)*DI + d]
// phase1: 128-thread blocks, grid (DI/128, NC, B_). CL = L_/NC = 32.
// ---------------------------------------------------------------------------
template<int S, int NC>
__global__ __launch_bounds__(128) void scan_p1(
        float* __restrict__ delta,        // in delta / out cumd
        const float* __restrict__ dbc,
        const ushort* __restrict__ xi,
        float* __restrict__ yloc,         // xz base (stride 2*DI)
        const float* __restrict__ A_log,
        float* __restrict__ dec,
        float* __restrict__ hfin) {
    const int CL = L_ / NC;               // 32
    const int d = blockIdx.x * 128 + threadIdx.x;
    const int c = blockIdx.y;
    const int b = blockIdx.z;
    float a[S], h[S];
    #pragma unroll
    for (int s = 0; s < S; s++) {
        a[s] = -__expf(A_log[d * S + s]);
        h[s] = 0.f;
    }
    float dsum = 0.f;
    __shared__ float bcs[16][128];
    const size_t row0 = (size_t)b * L_ + (size_t)c * CL;
    float*        dp = delta + row0 * DI + d;
    const ushort* xp = xi    + row0 * DI + d;
    float*        yp = yloc  + row0 * (2 * DI) + d;

    float dlt_pf = dp[0];
    ushort x_pf  = xp[0];

    for (int t = 0; t < CL; ++t) {
        if ((t & 15) == 0) {
            __syncthreads();
            const float4* src = (const float4*)(dbc + (row0 + t) * 128);
            float4* dst = (float4*)&bcs[0][0];
            #pragma unroll
            for (int j = 0; j < 4; j++)
                dst[threadIdx.x + 128 * j] = src[threadIdx.x + 128 * j];
            __syncthreads();
        }
        float dlt = dlt_pf;
        float x   = bf2f(x_pf);
        if (t + 1 < CL) {
            dlt_pf = dp[(size_t)(t + 1) * DI];
            x_pf   = xp[(size_t)(t + 1) * DI];
        }
        dsum += dlt;
        float dx = dlt * x;
        float p = 0.f;
        int tt = t & 15;
        #pragma unroll
        for (int s = 0; s < S; s++) {
            float e = __expf(dlt * a[s]);
            h[s] = e * h[s] + dx * bcs[tt][DTR + s];
            p += h[s] * bcs[tt][DTR + S + s];
        }
        yp[(size_t)t * (2 * DI)] = p;
        dp[(size_t)t * DI] = dsum;        // cumd overwrite
    }
    #pragma unroll
    for (int s = 0; s < S; s++) {
        size_t idx = (((size_t)b * NC + c) * S + s) * DI + d;
        dec[idx]  = __expf(a[s] * dsum);
        hfin[idx] = h[s];
    }
}

// phase2: sequential over chunks; hfin becomes h_start.
template<int S, int NC>
__global__ void scan_p2(const float* __restrict__ dec,
                        float* __restrict__ hfin) {
    int gid = blockIdx.x * 256 + threadIdx.x;   // (b*S+s)*DI + d
    int d = gid % DI;
    int s = (gid / DI) % S;
    int b = gid / (DI * S);
    float run = 0.f;
    #pragma unroll
    for (int c = 0; c < NC; ++c) {
        size_t idx = (((size_t)b * NC + c) * S + s) * DI + d;
        float dc = dec[idx];
        float hf = hfin[idx];
        hfin[idx] = run;
        run = dc * run + hf;
    }
}

// phase3: y = yloc + C.(exp(a*cumd)*h_start) + x*D, *= silu(z) -> bf16 (in place)
template<int S, int NC>
__global__ __launch_bounds__(256) void scan_p3(
        const float* __restrict__ cumd,
        const float* __restrict__ dbc,
        ushort* __restrict__ xi,            // read x / write u (in place)
        const float* __restrict__ xz,       // yloc + z
        const float* __restrict__ A_log,
        const float* __restrict__ Dp,
        const float* __restrict__ hstart) {
    const int CL = L_ / NC;
    const int d  = blockIdx.x * 256 + threadIdx.x;
    const int t0 = blockIdx.y * 16;
    const int b  = blockIdx.z;
    const int c  = t0 / CL;
    float a[S], hs[S];
    #pragma unroll
    for (int s = 0; s < S; s++) {
        a[s]  = -__expf(A_log[d * S + s]);
        hs[s] = hstart[(((size_t)b * NC + c) * S + s) * DI + d];
    }
    float Dv = Dp[d];
    __shared__ float bcs[16][128];
    {
        const float4* src = (const float4*)(dbc + ((size_t)b * L_ + t0) * 128);
        float4* dst = (float4*)&bcs[0][0];
        dst[threadIdx.x]       = src[threadIdx.x];
        dst[threadIdx.x + 256] = src[threadIdx.x + 256];
    }
    __syncthreads();
    #pragma unroll 1
    for (int tt = 0; tt < 16; ++tt) {
        size_t row = (size_t)b * L_ + t0 + tt;
        float cd = cumd[row * DI + d];
        float p = 0.f;
        #pragma unroll
        for (int s = 0; s < S; s++)
            p += __expf(a[s] * cd) * hs[s] * bcs[tt][DTR + S + s];
        float x  = bf2f(xi[row * DI + d]);
        float yl = xz[row * (2 * DI) + d];
        float z  = xz[row * (2 * DI) + DI + d];
        float y  = yl + p + x * Dv;
        float u  = y * (z / (1.f + __expf(-z)));
        xi[row * DI + d] = f2bf_rne(u);
    }
}

// ---------------------------------------------------------------------------
__global__ void pack_xc_bf16(const float* __restrict__ xs,
                             const float* __restrict__ xl,
                             ushort* __restrict__ xc) {
    int idx = blockIdx.x * 256 + threadIdx.x;
    int n = idx / (2 * DM);
    int m = idx % (2 * DM);
    float v = (m < DM) ? xs[(size_t)n * DM + m] : xl[(size_t)n * DM + m - DM];
    xc[idx] = f2bf_rne(v);
}

// ---------------------------------------------------------------------------
__global__ void fuse_ln_kernel(const float* __restrict__ xs,
                               const float* __restrict__ xl,
                               const float* __restrict__ gp,
                               const float* __restrict__ ln_w,
                               const float* __restrict__ ln_b,
                               float* __restrict__ out) {
    int n = blockIdx.x;
    float v[3];
    float sum = 0.f, sumsq = 0.f;
    #pragma unroll
    for (int j = 0; j < 3; j++) {
        int m = threadIdx.x + 256 * j;
        float g    = gp[(size_t)n * (2 * DM) + m];
        float gate = 1.f / (1.f + __expf(-g));
        float p    = gp[(size_t)n * (2 * DM) + DM + m];
        float val  = gate * xs[(size_t)n * DM + m]
                   + (1.f - gate) * xl[(size_t)n * DM + m] + p;
        v[j] = val;
        sum += val; sumsq += val * val;
    }
    blockReduce2(sum, sumsq);
    float mean = sum / DM;
    float var  = sumsq / DM - mean * mean;
    float inv  = rsqrtf(var + 1e-5f);
    #pragma unroll
    for (int j = 0; j < 3; j++) {
        int m = threadIdx.x + 256 * j;
        out[(size_t)n * DM + m] = (v[j] - mean) * inv * ln_w[m] + ln_b[m];
    }
}

// ---------------------------------------------------------------------------
extern "C" void kernel_launch(void* const* d_in, const int* in_sizes, int n_in,
                              void* d_out, int out_size, void* d_ws, size_t ws_size,
                              hipStream_t stream) {
    const float* x      = (const float*)d_in[0];
    const float* gate_w = (const float*)d_in[21];
    const float* gate_b = (const float*)d_in[22];
    const float* proj_w = (const float*)d_in[23];
    const float* proj_b = (const float*)d_in[24];
    const float* ln_w   = (const float*)d_in[25];
    const float* ln_b   = (const float*)d_in[26];

    float* ws = (float*)d_ws;
    size_t off = 0;
    float* xs    = ws + off; off += (size_t)NTOK * DM;        // 1.57M f
    float* xl    = ws + off; off += (size_t)NTOK * DM;
    float* xz    = ws + off; off += (size_t)NTOK * 2 * DI;    // 6.29M f
    float* dbc   = ws + off; off += (size_t)NTOK * 128;
    float* delta = ws + off; off += (size_t)NTOK * DI;
    ushort* xn_bf = (ushort*)(ws + off); off += (size_t)NTOK * DM / 2;
    ushort* xi_bf = (ushort*)(ws + off); off += (size_t)NTOK * DI / 2;
    float* dec  = ws + off; off += (size_t)B_ * DI * 32 * NCC;   // 3.15M f
    float* hfin = ws + off; off += (size_t)B_ * DI * 32 * NCC;   // 3.15M f
    // total ~21.5M floats = 86 MB

    ushort* wbuf  = (ushort*)dec;    // bf16 weight scratch (temporally disjoint)
    ushort* xw_bf = (ushort*)hfin;   // bf16 x_w scratch (dead before p1 writes)

    copy2_kernel<<<(NTOK * DM) / 256, 256, 0, stream>>>(x, xs, xl);

    for (int br = 0; br < 2; ++br) {
        const float* in_w   = (const float*)d_in[1 + 10 * br + 0];
        const float* conv_w = (const float*)d_in[1 + 10 * br + 1];
        const float* conv_b = (const float*)d_in[1 + 10 * br + 2];
        const float* x_w    = (const float*)d_in[1 + 10 * br + 3];
        const float* dt_w   = (const float*)d_in[1 + 10 * br + 4];
        const float* dt_b   = (const float*)d_in[1 + 10 * br + 5];
        const float* A_log  = (const float*)d_in[1 + 10 * br + 6];
        const float* Dp     = (const float*)d_in[1 + 10 * br + 7];
        const float* out_w  = (const float*)d_in[1 + 10 * br + 8];
        const float* norm_w = (const float*)d_in[1 + 10 * br + 9];
        const int S = br ? 32 : 16;
        const int Mdbc = DTR + 2 * S;    // 80 / 112
        float* xbuf = br ? xl : xs;

        for (int i = 0; i < NL; ++i) {
            rmsnorm_bf16<<<NTOK, 256, 0, stream>>>(xbuf, norm_w + i * DM, xn_bf);

            f2bf_kernel<<<(2 * DI * DM / 4 + 255) / 256, 256, 0, stream>>>(
                in_w + (size_t)i * 2 * DI * DM, wbuf, 2 * DI * DM / 4);
            gemm_bf16_mfma<false, false><<<dim3(NTOK / 128, 2 * DI / 128), 256, 0, stream>>>(
                xn_bf, wbuf, nullptr, xz, 2 * DI, DM);

            if (br == 0)
                conv_silu_kernel<3><<<(NTOK * DI) / 256, 256, 0, stream>>>(
                    xz, conv_w + i * DI * 3, conv_b + i * DI, xi_bf);
            else
                conv_silu_kernel<9><<<(NTOK * DI) / 256, 256, 0, stream>>>(
                    xz, conv_w + i * DI * 9, conv_b + i * DI, xi_bf);

            // x_w GEMM in bf16 MFMA (M-guarded)
            f2bf_kernel<<<(Mdbc * DI / 4 + 255) / 256, 256, 0, stream>>>(
                x_w + (size_t)i * Mdbc * DI, xw_bf, Mdbc * DI / 4);
            gemm_bf16_mfma_xw<<<NTOK / 128, 256, 0, stream>>>(
                xi_bf, xw_bf, dbc, Mdbc, DI);

            dim3 g3(NTOK / 64, DI / 64);
            gemm_nt<1, true, false><<<g3, 256, 0, stream>>>(
                dbc, 128, dt_w + (size_t)i * DI * DTR, dt_b + i * DI,
                delta, DI, DI, DTR);

            // ---- chunked scan (NC=32, CL=32) ----
            if (br == 0) {
                scan_p1<16, NCC><<<dim3(DI / 128, NCC, B_), 128, 0, stream>>>(
                    delta, dbc, xi_bf, xz, A_log + (size_t)i * DI * 16, dec, hfin);
                scan_p2<16, NCC><<<(B_ * 16 * DI) / 256, 256, 0, stream>>>(dec, hfin);
                scan_p3<16, NCC><<<dim3(DI / 256, L_ / 16, B_), 256, 0, stream>>>(
                    delta, dbc, xi_bf, xz, A_log + (size_t)i * DI * 16,
                    Dp + i * DI, hfin);
            } else {
                scan_p1<32, NCC><<<dim3(DI / 128, NCC, B_), 128, 0, stream>>>(
                    delta, dbc, xi_bf, xz, A_log + (size_t)i * DI * 32, dec, hfin);
                scan_p2<32, NCC><<<(B_ * 32 * DI) / 256, 256, 0, stream>>>(dec, hfin);
                scan_p3<32, NCC><<<dim3(DI / 256, L_ / 16, B_), 256, 0, stream>>>(
                    delta, dbc, xi_bf, xz, A_log + (size_t)i * DI * 32,
                    Dp + i * DI, hfin);
            }

            // out_w GEMM (768 cols) on 128x64 tiles, residual add
            f2bf_kernel<<<(DM * DI / 4 + 255) / 256, 256, 0, stream>>>(
                out_w + (size_t)i * DM * DI, wbuf, DM * DI / 4);
            gemm_bf16_mfma_64<false, true><<<dim3(NTOK / 128, DM / 64), 256, 0, stream>>>(
                xi_bf, wbuf, nullptr, xbuf, DM, DI);
        }
    }

    // ---- fusion head ----
    ushort* xc_bf = xi_bf;
    float* gp = xz;
    pack_xc_bf16<<<(NTOK * 2 * DM) / 256, 256, 0, stream>>>(xs, xl, xc_bf);

    f2bf_kernel<<<(DM * 2 * DM / 4 + 255) / 256, 256, 0, stream>>>(
        gate_w, wbuf, DM * 2 * DM / 4);
    gemm_bf16_mfma_64<true, false><<<dim3(NTOK / 128, DM / 64), 256, 0, stream>>>(
        xc_bf, wbuf, gate_b, gp, 2 * DM, 2 * DM);
    f2bf_kernel<<<(DM * 2 * DM / 4 + 255) / 256, 256, 0, stream>>>(
        proj_w, wbuf, DM * 2 * DM / 4);
    gemm_bf16_mfma_64<true, false><<<dim3(NTOK / 128, DM / 64), 256, 0, stream>>>(
        xc_bf, wbuf, proj_b, gp + DM, 2 * DM, 2 * DM);

    fuse_ln_kernel<<<NTOK, 256, 0, stream>>>(
        xs, xl, gp, ln_w, ln_b, (float*)d_out);
}